// Round 4
// baseline (214.450 us; speedup 1.0000x reference)
//
#include <hip/hip_runtime.h>
#include <math.h>

// Problem constants
#define T_DIM 8192
#define N_DIM 4096
#define L 64
#define P 32
#define IN_DIM 192
#define S_CHUNK 16
#define N_CHUNK (T_DIM / S_CHUNK)   // 512
#define LDSTRIDE 66

using f32x4   = __attribute__((ext_vector_type(4))) float;
using bf16x8  = __attribute__((ext_vector_type(8))) short;
using ushort8 = __attribute__((ext_vector_type(8))) unsigned short;

__device__ __forceinline__ unsigned short f2bf(float x) {
  unsigned u = __float_as_uint(x);
  u += 0x7fffu + ((u >> 16) & 1u);           // round-to-nearest-even
  return (unsigned short)(u >> 16);
}
__device__ __forceinline__ float bf2f(unsigned short h) {
  return __uint_as_float(((unsigned)h) << 16);
}

// ---------------- kernel A: partial sums for xh0 = U^T x0 ----------------
__global__ __launch_bounds__(64) void k_xh0_part(const float* __restrict__ U,
                                                 const float* __restrict__ Xtr,
                                                 float* __restrict__ part) {
  int b = blockIdx.x;
  int l = threadIdx.x;
  int n0 = b * 64;
  float acc = 0.f;
  #pragma unroll 8
  for (int i = 0; i < 64; ++i) {
    float x = Xtr[n0 + i];
    acc += U[(size_t)(n0 + i) * L + l] * x;
  }
  part[b * 64 + l] = acc;
}

// ---------------- kernel A2: split U into bf16 hi/lo ([n][k] layout) ----------------
__global__ __launch_bounds__(256) void k_usplit(const float* __restrict__ U,
                                                unsigned short* __restrict__ uh,
                                                unsigned short* __restrict__ ul) {
  int i = blockIdx.x * 256 + threadIdx.x;     // grid covers N*L exactly
  float x = U[i];
  unsigned short h = f2bf(x);
  unsigned short lo = f2bf(x - bf2f(h));
  uh[i] = h; ul[i] = lo;
}

// ---------------- kernel B: argmax, temp, build M, xh0, matrix doublings ----------------
__global__ __launch_bounds__(256) void k_prep(const float* __restrict__ A_tilde,
                                              const float* __restrict__ phi_bar_t,
                                              const float* __restrict__ logits,
                                              const float* __restrict__ temp,
                                              const float* __restrict__ part,
                                              float* __restrict__ Wm,
                                              float* __restrict__ xh0,
                                              float* __restrict__ out_tail) {
  __shared__ float buf[2][64 * LDSTRIDE];
  __shared__ int sel_s[P];
  int tid = threadIdx.x;

  if (tid < P) {
    const float* row = logits + tid * IN_DIM;
    float best = row[0]; int bi = 0;
    for (int k = 1; k < IN_DIM; ++k) { float v = row[k]; if (v > best) { best = v; bi = k; } }
    sel_s[tid] = bi;
    out_tail[2 + tid] = (float)bi;
  }
  if (tid == 0) out_tail[1] = fmaxf(0.01f, temp[0] * 0.999f);

  for (int i = tid; i < L * L; i += 256)
    buf[0][(i >> 6) * LDSTRIDE + (i & 63)] = A_tilde[i];
  __syncthreads();

  if (tid < L) {
    for (int p = 0; p < P; ++p) {
      int kk = sel_s[p]; if (kk > L - 1) kk = L - 1;
      buf[0][tid * LDSTRIDE + kk] += phi_bar_t[p * L + tid];
    }
  }
  if (tid >= 64 && tid < 128) {
    int l = tid - 64; float s = 0.f;
    for (int b = 0; b < 64; ++b) s += part[b * 64 + l];
    xh0[l] = s;
  }
  __syncthreads();

  for (int i = tid; i < L * L; i += 256)
    Wm[i] = buf[0][(i >> 6) * LDSTRIDE + (i & 63)];

  // 12 sequential squarings; a-value read inline from LDS (no 64-elem array)
  int r = tid & 63, cg = tid >> 6;
  int c0 = cg * 16;
  int cur = 0;
  for (int j = 1; j <= 12; ++j) {
    const float* S = buf[cur];
    float* D = buf[cur ^ 1];
    float acc[16];
    #pragma unroll
    for (int c = 0; c < 16; ++c) acc[c] = 0.f;
    #pragma unroll 8
    for (int k = 0; k < 64; ++k) {
      float av = S[r * LDSTRIDE + k];                 // 2-way bank = free
      const float2* bp = (const float2*)(S + k * LDSTRIDE + c0); // broadcast
      #pragma unroll
      for (int c2 = 0; c2 < 8; ++c2) {
        float2 b2 = bp[c2];
        acc[2 * c2]     += av * b2.x;
        acc[2 * c2 + 1] += av * b2.y;
      }
    }
    #pragma unroll
    for (int c = 0; c < 16; ++c) D[r * LDSTRIDE + c0 + c] = acc[c];
    float* Wout = Wm + j * 4096;
    #pragma unroll
    for (int c = 0; c < 16; ++c) Wout[r * 64 + c0 + c] = acc[c];
    __syncthreads();
    cur ^= 1;
  }
}

// ---------------- kernel C: states via checkpoints, emit bf16 hi/lo [t][k] ----------------
__global__ __launch_bounds__(64) void k_states(const float* __restrict__ Wm,
                                               const float* __restrict__ xh0,
                                               unsigned short* __restrict__ xhi,
                                               unsigned short* __restrict__ xlo) {
  int c = blockIdx.x;       // 512 chunks of 16 steps
  int l = threadIdx.x;
  float v = xh0[l];
  int e = c << 4;
  for (int j = 4; j <= 12; ++j) {
    if ((e >> j) & 1) {
      const float* W = Wm + j * 4096;
      float n0 = 0.f, n1 = 0.f, n2 = 0.f, n3 = 0.f;
      #pragma unroll
      for (int k = 0; k < 64; k += 4) {
        n0 += W[l * 64 + k]     * __shfl(v, k, 64);
        n1 += W[l * 64 + k + 1] * __shfl(v, k + 1, 64);
        n2 += W[l * 64 + k + 2] * __shfl(v, k + 2, 64);
        n3 += W[l * 64 + k + 3] * __shfl(v, k + 3, 64);
      }
      v = (n0 + n1) + (n2 + n3);
    }
  }
  float m[64];
  #pragma unroll
  for (int k = 0; k < 64; ++k) m[k] = Wm[l * 64 + k];
  int t0 = c * S_CHUNK;
  for (int i = 0; i < S_CHUNK; ++i) {
    float n0 = 0.f, n1 = 0.f, n2 = 0.f, n3 = 0.f;
    #pragma unroll
    for (int k = 0; k < 64; k += 4) {
      n0 += m[k]     * __shfl(v, k, 64);
      n1 += m[k + 1] * __shfl(v, k + 1, 64);
      n2 += m[k + 2] * __shfl(v, k + 2, 64);
      n3 += m[k + 3] * __shfl(v, k + 3, 64);
    }
    v = (n0 + n1) + (n2 + n3);
    unsigned short h = f2bf(v);
    unsigned short lo = f2bf(v - bf2f(h));
    size_t base = (size_t)(t0 + i) * L + l;   // [t][k] layout, coalesced
    xhi[base] = h; xlo[base] = lo;
  }
}

// ---------------- kernel D: X_rec via bf16-split MFMA GEMM (K_eff=192), fused err ----------------
// C = X(8192x64) * U^T(64x4096) as [X_hi|X_lo|X_hi] x [U_hi;U_hi;U_lo], f32 accum.
// Block: 256 thr (4 waves 2x2), tile 128t x 128n; wave = 64x64 via 4x4 frags of
// 16x16x32. LDS rows [t|n][hi 128B | lo 128B], 16B-XOR-swizzled by ((row&7)<<4):
// fragment reads are bank-balanced (8 dw/bank per instr, structural minimum).
__global__ __launch_bounds__(256, 2) void k_xrec(const unsigned short* __restrict__ xhi,
                                                 const unsigned short* __restrict__ xlo,
                                                 const unsigned short* __restrict__ uh,
                                                 const unsigned short* __restrict__ ul,
                                                 const float* __restrict__ Y,
                                                 float* __restrict__ Xrec,
                                                 double* __restrict__ acc_g) {
  __shared__ __align__(16) unsigned short Xs[128 * 128];  // 32 KiB
  __shared__ __align__(16) unsigned short Us[128 * 128];  // 32 KiB
  __shared__ float red[512];

  int tid = threadIdx.x;
  int nt = blockIdx.x & 31, tt = blockIdx.x >> 5;
  int n0 = nt * 128, t0 = tt * 128;

  // stage A-tile: row t = [xhi[t0+t][0..63] | xlo[t0+t][0..63]]
  #pragma unroll
  for (int i = 0; i < 8; ++i) {
    int c = tid + 256 * i;
    int t = c >> 4, p = c & 15;
    const ushort8* src = (p < 8)
      ? (const ushort8*)(xhi + (size_t)(t0 + t) * L + p * 8)
      : (const ushort8*)(xlo + (size_t)(t0 + t) * L + (p - 8) * 8);
    *(ushort8*)((char*)Xs + t * 256 + ((p * 16) ^ ((t & 7) << 4))) = *src;
  }
  // stage B-tile: row n = [uh[n0+n][0..63] | ul[n0+n][0..63]]
  #pragma unroll
  for (int i = 0; i < 8; ++i) {
    int c = tid + 256 * i;
    int nn = c >> 4, p = c & 15;
    const ushort8* src = (p < 8)
      ? (const ushort8*)(uh + (size_t)(n0 + nn) * L + p * 8)
      : (const ushort8*)(ul + (size_t)(n0 + nn) * L + (p - 8) * 8);
    *(ushort8*)((char*)Us + nn * 256 + ((p * 16) ^ ((nn & 7) << 4))) = *src;
  }
  __syncthreads();

  int l = tid & 63, wid = tid >> 6;
  int wr = wid >> 1, wc = wid & 1;
  int lr = l & 15, lg = l >> 4;

  f32x4 acc[4][4];
  #pragma unroll
  for (int m = 0; m < 4; ++m)
    #pragma unroll
    for (int nf = 0; nf < 4; ++nf) acc[m][nf] = (f32x4){0.f, 0.f, 0.f, 0.f};

  // k-step plan: s0,1 = hi*hi (k 0..63); s2,3 = lo*hi; s4,5 = hi*lo
  const int KA[6] = {0, 32, 64, 96, 0, 32};
  const int KB[6] = {0, 32, 0, 32, 64, 96};
  #pragma unroll
  for (int s = 0; s < 6; ++s) {
    bf16x8 af[4], bfr[4];
    #pragma unroll
    for (int m = 0; m < 4; ++m) {
      int t_loc = wr * 64 + m * 16 + lr;
      int kk = KA[s] + lg * 8;
      af[m] = *(const bf16x8*)((const char*)Xs + t_loc * 256 + ((kk * 2) ^ ((t_loc & 7) << 4)));
    }
    #pragma unroll
    for (int nf = 0; nf < 4; ++nf) {
      int n_loc = wc * 64 + nf * 16 + lr;
      int kk = KB[s] + lg * 8;
      bfr[nf] = *(const bf16x8*)((const char*)Us + n_loc * 256 + ((kk * 2) ^ ((n_loc & 7) << 4)));
    }
    #pragma unroll
    for (int m = 0; m < 4; ++m)
      #pragma unroll
      for (int nf = 0; nf < 4; ++nf)
        acc[m][nf] = __builtin_amdgcn_mfma_f32_16x16x32_bf16(af[m], bfr[nf], acc[m][nf], 0, 0, 0);
  }

  // epilogue: C/D layout col=lane&15, row=(lane>>4)*4+reg  [m89-verified]
  float sd = 0.f, sy = 0.f;
  #pragma unroll
  for (int m = 0; m < 4; ++m) {
    #pragma unroll
    for (int nf = 0; nf < 4; ++nf) {
      #pragma unroll
      for (int r = 0; r < 4; ++r) {
        int t = t0 + wr * 64 + m * 16 + lg * 4 + r;
        int n = n0 + wc * 64 + nf * 16 + lr;
        size_t idx = (size_t)t * N_DIM + n;
        float x = acc[m][nf][r];
        float y = Y[idx];
        float d = y - x;
        sd += d * d; sy += y * y;
        Xrec[idx] = x;
      }
    }
  }

  red[tid] = sd; red[256 + tid] = sy;
  __syncthreads();
  for (int s2 = 128; s2 > 0; s2 >>= 1) {
    if (tid < s2) { red[tid] += red[tid + s2]; red[256 + tid] += red[256 + tid + s2]; }
    __syncthreads();
  }
  if (tid == 0) {
    atomicAdd(acc_g,     (double)red[0]);
    atomicAdd(acc_g + 1, (double)red[256]);
  }
}

// ---------------- kernel E: finalize err ----------------
__global__ void k_err(const double* __restrict__ acc, float* __restrict__ out_tail) {
  out_tail[0] = (float)sqrt(acc[0] / acc[1]);
}

extern "C" void kernel_launch(void* const* d_in, const int* in_sizes, int n_in,
                              void* d_out, int out_size, void* d_ws, size_t ws_size,
                              hipStream_t stream) {
  const float* X_train = (const float*)d_in[1];
  const float* Y       = (const float*)d_in[2];
  const float* temp    = (const float*)d_in[3];
  const float* phi     = (const float*)d_in[4];
  const float* A_tilde = (const float*)d_in[5];
  const float* U       = (const float*)d_in[6];
  const float* logits  = (const float*)d_in[7];
  float* out = (float*)d_out;
  float* out_tail = out + (size_t)T_DIM * N_DIM;

  // workspace layout (bytes)
  char* w = (char*)d_ws;
  double* acc          = (double*)w;                     // @0, 16 B
  float* Wm            = (float*)(w + 64);               // 13*16384 B -> ends 213056
  float* xh0           = (float*)(w + 213056);           // 256 B
  float* part          = (float*)(w + 213312);           // 16384 B -> ends 229696
  unsigned short* uh   = (unsigned short*)(w + 262144);  // 512 KiB
  unsigned short* ul   = (unsigned short*)(w + 786432);  // 512 KiB
  unsigned short* xhi  = (unsigned short*)(w + 1310720); // 1 MiB
  unsigned short* xlo  = (unsigned short*)(w + 2359296); // 1 MiB -> ends 3407872

  hipMemsetAsync(acc, 0, 2 * sizeof(double), stream);

  k_xh0_part<<<64, 64, 0, stream>>>(U, X_train, part);
  k_usplit<<<(N_DIM * L) / 256, 256, 0, stream>>>(U, uh, ul);
  k_prep<<<1, 256, 0, stream>>>(A_tilde, phi, logits, temp, part, Wm, xh0, out_tail);
  k_states<<<N_CHUNK, 64, 0, stream>>>(Wm, xh0, xhi, xlo);
  k_xrec<<<2048, 256, 0, stream>>>(xhi, xlo, uh, ul, Y, out, acc);
  k_err<<<1, 1, 0, stream>>>(acc, out_tail);
}

// Round 5
// 127.816 us; speedup vs baseline: 1.6778x; 1.6778x over previous
//
#include <hip/hip_runtime.h>
#include <math.h>

// Problem constants
#define T_DIM 8192
#define N_DIM 4096
#define L 64
#define P 32
#define IN_DIM 192
#define S_CHUNK 16
#define N_CHUNK (T_DIM / S_CHUNK)   // 512
#define LDST 68                     // padded LDS row stride (float4-aligned)

using f32x4   = __attribute__((ext_vector_type(4))) float;
using bf16x8  = __attribute__((ext_vector_type(8))) short;
using ushort8 = __attribute__((ext_vector_type(8))) unsigned short;

__device__ __forceinline__ unsigned short f2bf(float x) {
  unsigned u = __float_as_uint(x);
  u += 0x7fffu + ((u >> 16) & 1u);           // round-to-nearest-even
  return (unsigned short)(u >> 16);
}
__device__ __forceinline__ float bf2f(unsigned short h) {
  return __uint_as_float(((unsigned)h) << 16);
}

// ---------------- kernel A: partial sums for xh0 = U^T x0; also zeroes acc ----------------
__global__ __launch_bounds__(64) void k_xh0_part(const float* __restrict__ U,
                                                 const float* __restrict__ Xtr,
                                                 float* __restrict__ part,
                                                 double* __restrict__ acc) {
  int b = blockIdx.x;
  int l = threadIdx.x;
  if (b == 0 && l < 2) acc[l] = 0.0;           // replaces hipMemsetAsync
  int n0 = b * 64;
  float s = 0.f;
  #pragma unroll 8
  for (int i = 0; i < 64; ++i) {
    float x = Xtr[n0 + i];
    s += U[(size_t)(n0 + i) * L + l] * x;
  }
  part[b * 64 + l] = s;
}

// ---------------- kernel A2: split U into bf16 hi/lo ([n][k] layout), float4 ----------------
__global__ __launch_bounds__(256) void k_usplit(const float* __restrict__ U,
                                                unsigned short* __restrict__ uh,
                                                unsigned short* __restrict__ ul) {
  int i = blockIdx.x * 256 + threadIdx.x;      // over N*L/4 float4s
  float4 x = ((const float4*)U)[i];
  ushort4 h, lo;
  h.x = f2bf(x.x); lo.x = f2bf(x.x - bf2f(h.x));
  h.y = f2bf(x.y); lo.y = f2bf(x.y - bf2f(h.y));
  h.z = f2bf(x.z); lo.z = f2bf(x.z - bf2f(h.z));
  h.w = f2bf(x.w); lo.w = f2bf(x.w - bf2f(h.w));
  ((ushort4*)uh)[i] = h;
  ((ushort4*)ul)[i] = lo;
}

// ---------------- kernel B: argmax, temp, build M, xh0, matrix doublings ----------------
// One block, 256 threads (4 waves, 1/SIMD). Phase 1 is all coalesced float4
// loads with high ILP (round-4 lesson: serial scalar global loads at 1
// wave/SIMD cost ~900 cyc each, ~70 us for the old argmax alone).
__global__ __launch_bounds__(256, 1) void k_prep(const float* __restrict__ A_tilde,
                                                 const float* __restrict__ phi_bar_t,
                                                 const float* __restrict__ logits,
                                                 const float* __restrict__ temp,
                                                 const float* __restrict__ part,
                                                 float* __restrict__ Wm,
                                                 float* __restrict__ xh0,
                                                 float* __restrict__ out_tail) {
  __shared__ float buf[2][64 * LDST];   // 34816 B
  __shared__ float sphi[P * L];         // 8192 B
  __shared__ float spart[4 * 64];       // 1024 B
  __shared__ int   sel_s[P];
  int tid = threadIdx.x;

  // ---- phase 1a: A_tilde -> buf[0] (float4, coalesced) ----
  #pragma unroll
  for (int i = 0; i < 4; ++i) {
    int f = tid + 256 * i;              // f4 index 0..1023
    int r = f >> 4, q = f & 15;
    float4 v = ((const float4*)A_tilde)[f];
    *(float4*)(buf[0] + r * LDST + q * 4) = v;
  }
  // ---- phase 1b: phi -> sphi (float4) ----
  #pragma unroll
  for (int i = 0; i < 2; ++i) {
    int f = tid + 256 * i;              // 0..511
    ((float4*)sphi)[f] = ((const float4*)phi_bar_t)[f];
  }
  // ---- phase 1c: part partial-reduce (coalesced, 4-way parallel over q) ----
  {
    int l = tid & 63, q = tid >> 6;
    float s = 0.f;
    #pragma unroll
    for (int i = 0; i < 16; ++i)
      s += part[(q * 16 + i) * 64 + l];
    spart[q * 64 + l] = s;
  }
  // ---- phase 1d: argmax per logits row; 8-lane groups, float4 reads ----
  {
    int p = tid >> 3, d = tid & 7;      // row, lane-in-group
    const float* row = logits + p * IN_DIM;
    float best = -1e30f; int bk = 0;
    #pragma unroll
    for (int j = 0; j < 6; ++j) {
      int kb = (j * 8 + d) * 4;
      float4 v = *(const float4*)(row + kb);
      if (v.x > best) { best = v.x; bk = kb; }
      if (v.y > best) { best = v.y; bk = kb + 1; }
      if (v.z > best) { best = v.z; bk = kb + 2; }
      if (v.w > best) { best = v.w; bk = kb + 3; }
    }
    #pragma unroll
    for (int off = 4; off > 0; off >>= 1) {
      float vo = __shfl_down(best, off, 8);
      int   ko = __shfl_down(bk,   off, 8);
      if (vo > best || (vo == best && ko < bk)) { best = vo; bk = ko; }
    }
    if (d == 0) {
      sel_s[p] = bk;
      out_tail[2 + p] = (float)bk;
    }
  }
  if (tid == 255) out_tail[1] = fmaxf(0.01f, temp[0] * 0.999f);
  __syncthreads();

  // ---- phase 2: scatter phi into M rows; finish xh0 ----
  if (tid < L) {
    #pragma unroll 4
    for (int p = 0; p < P; ++p) {
      int kk = sel_s[p]; if (kk > L - 1) kk = L - 1;
      buf[0][tid * LDST + kk] += sphi[p * L + tid];
    }
  } else if (tid < 128) {
    int l = tid - 64;
    xh0[l] = spart[l] + spart[64 + l] + spart[128 + l] + spart[192 + l];
  }
  __syncthreads();

  // ---- phase 3: W_0 = M out; 12 squarings with 4x4 register blocking ----
  #pragma unroll
  for (int i = 0; i < 4; ++i) {
    int f = tid + 256 * i;
    int r = f >> 4, q = f & 15;
    *(float4*)(Wm + r * 64 + q * 4) = *(const float4*)(buf[0] + r * LDST + q * 4);
  }

  int r0 = (tid >> 4) << 2;   // 0..60 (wave w owns rows 16w..16w+15)
  int c0 = (tid & 15) << 2;   // 0..60
  int cur = 0;
  for (int j = 1; j <= 12; ++j) {
    const float* S = buf[cur];
    float* D = buf[cur ^ 1];
    float acc[4][4];
    #pragma unroll
    for (int i = 0; i < 4; ++i)
      #pragma unroll
      for (int c = 0; c < 4; ++c) acc[i][c] = 0.f;

    #pragma unroll
    for (int kb = 0; kb < 64; kb += 16) {
      float a[4][16];
      #pragma unroll
      for (int i = 0; i < 4; ++i)
        #pragma unroll
        for (int q = 0; q < 4; ++q) {
          float4 t4 = *(const float4*)(S + (r0 + i) * LDST + kb + q * 4);
          a[i][q * 4 + 0] = t4.x; a[i][q * 4 + 1] = t4.y;
          a[i][q * 4 + 2] = t4.z; a[i][q * 4 + 3] = t4.w;
        }
      #pragma unroll
      for (int kk = 0; kk < 16; ++kk) {
        float4 b4 = *(const float4*)(S + (kb + kk) * LDST + c0);
        #pragma unroll
        for (int i = 0; i < 4; ++i) {
          acc[i][0] += a[i][kk] * b4.x;
          acc[i][1] += a[i][kk] * b4.y;
          acc[i][2] += a[i][kk] * b4.z;
          acc[i][3] += a[i][kk] * b4.w;
        }
      }
    }
    #pragma unroll
    for (int i = 0; i < 4; ++i) {
      float4 o = {acc[i][0], acc[i][1], acc[i][2], acc[i][3]};
      *(float4*)(D + (r0 + i) * LDST + c0) = o;
      *(float4*)(Wm + j * 4096 + (r0 + i) * 64 + c0) = o;
    }
    __syncthreads();
    cur ^= 1;
  }
}

// ---------------- kernel C: states via checkpoints, emit bf16 hi/lo [t][k] ----------------
__global__ __launch_bounds__(64) void k_states(const float* __restrict__ Wm,
                                               const float* __restrict__ xh0,
                                               unsigned short* __restrict__ xhi,
                                               unsigned short* __restrict__ xlo) {
  int c = blockIdx.x;       // 512 chunks of 16 steps
  int l = threadIdx.x;
  float v = xh0[l];
  int e = c << 4;
  for (int j = 4; j <= 12; ++j) {
    if ((e >> j) & 1) {
      const float* W = Wm + j * 4096;
      float n0 = 0.f, n1 = 0.f, n2 = 0.f, n3 = 0.f;
      #pragma unroll
      for (int k = 0; k < 64; k += 4) {
        n0 += W[l * 64 + k]     * __shfl(v, k, 64);
        n1 += W[l * 64 + k + 1] * __shfl(v, k + 1, 64);
        n2 += W[l * 64 + k + 2] * __shfl(v, k + 2, 64);
        n3 += W[l * 64 + k + 3] * __shfl(v, k + 3, 64);
      }
      v = (n0 + n1) + (n2 + n3);
    }
  }
  float m[64];
  #pragma unroll
  for (int k = 0; k < 64; ++k) m[k] = Wm[l * 64 + k];
  int t0 = c * S_CHUNK;
  for (int i = 0; i < S_CHUNK; ++i) {
    float n0 = 0.f, n1 = 0.f, n2 = 0.f, n3 = 0.f;
    #pragma unroll
    for (int k = 0; k < 64; k += 4) {
      n0 += m[k]     * __shfl(v, k, 64);
      n1 += m[k + 1] * __shfl(v, k + 1, 64);
      n2 += m[k + 2] * __shfl(v, k + 2, 64);
      n3 += m[k + 3] * __shfl(v, k + 3, 64);
    }
    v = (n0 + n1) + (n2 + n3);
    unsigned short h = f2bf(v);
    unsigned short lo = f2bf(v - bf2f(h));
    size_t base = (size_t)(t0 + i) * L + l;   // [t][k] layout, coalesced
    xhi[base] = h; xlo[base] = lo;
  }
}

// ---------------- kernel D: X_rec via bf16-split MFMA GEMM (K_eff=192), fused err ----------------
// C = X(8192x64) * U^T(64x4096) as [X_hi|X_lo|X_hi] x [U_hi;U_hi;U_lo], f32 accum.
// Block: 256 thr (4 waves 2x2), tile 128t x 128n; wave = 64x64 via 4x4 frags of
// 16x16x32. LDS rows [t|n][hi 128B | lo 128B], 16B-XOR-swizzled by ((row&7)<<4).
__global__ __launch_bounds__(256, 2) void k_xrec(const unsigned short* __restrict__ xhi,
                                                 const unsigned short* __restrict__ xlo,
                                                 const unsigned short* __restrict__ uh,
                                                 const unsigned short* __restrict__ ul,
                                                 const float* __restrict__ Y,
                                                 float* __restrict__ Xrec,
                                                 double* __restrict__ acc_g) {
  __shared__ __align__(16) unsigned short Xs[128 * 128];  // 32 KiB
  __shared__ __align__(16) unsigned short Us[128 * 128];  // 32 KiB
  __shared__ float red[512];

  int tid = threadIdx.x;
  int nt = blockIdx.x & 31, tt = blockIdx.x >> 5;
  int n0 = nt * 128, t0 = tt * 128;

  // stage A-tile: row t = [xhi[t0+t][0..63] | xlo[t0+t][0..63]]
  #pragma unroll
  for (int i = 0; i < 8; ++i) {
    int c = tid + 256 * i;
    int t = c >> 4, p = c & 15;
    const ushort8* src = (p < 8)
      ? (const ushort8*)(xhi + (size_t)(t0 + t) * L + p * 8)
      : (const ushort8*)(xlo + (size_t)(t0 + t) * L + (p - 8) * 8);
    *(ushort8*)((char*)Xs + t * 256 + ((p * 16) ^ ((t & 7) << 4))) = *src;
  }
  // stage B-tile: row n = [uh[n0+n][0..63] | ul[n0+n][0..63]]
  #pragma unroll
  for (int i = 0; i < 8; ++i) {
    int c = tid + 256 * i;
    int nn = c >> 4, p = c & 15;
    const ushort8* src = (p < 8)
      ? (const ushort8*)(uh + (size_t)(n0 + nn) * L + p * 8)
      : (const ushort8*)(ul + (size_t)(n0 + nn) * L + (p - 8) * 8);
    *(ushort8*)((char*)Us + nn * 256 + ((p * 16) ^ ((nn & 7) << 4))) = *src;
  }
  __syncthreads();

  int l = tid & 63, wid = tid >> 6;
  int wr = wid >> 1, wc = wid & 1;
  int lr = l & 15, lg = l >> 4;

  f32x4 acc[4][4];
  #pragma unroll
  for (int m = 0; m < 4; ++m)
    #pragma unroll
    for (int nf = 0; nf < 4; ++nf) acc[m][nf] = (f32x4){0.f, 0.f, 0.f, 0.f};

  // k-step plan: s0,1 = hi*hi (k 0..63); s2,3 = lo*hi; s4,5 = hi*lo
  const int KA[6] = {0, 32, 64, 96, 0, 32};
  const int KB[6] = {0, 32, 0, 32, 64, 96};
  #pragma unroll
  for (int s = 0; s < 6; ++s) {
    bf16x8 af[4], bfr[4];
    #pragma unroll
    for (int m = 0; m < 4; ++m) {
      int t_loc = wr * 64 + m * 16 + lr;
      int kk = KA[s] + lg * 8;
      af[m] = *(const bf16x8*)((const char*)Xs + t_loc * 256 + ((kk * 2) ^ ((t_loc & 7) << 4)));
    }
    #pragma unroll
    for (int nf = 0; nf < 4; ++nf) {
      int n_loc = wc * 64 + nf * 16 + lr;
      int kk = KB[s] + lg * 8;
      bfr[nf] = *(const bf16x8*)((const char*)Us + n_loc * 256 + ((kk * 2) ^ ((n_loc & 7) << 4)));
    }
    #pragma unroll
    for (int m = 0; m < 4; ++m)
      #pragma unroll
      for (int nf = 0; nf < 4; ++nf)
        acc[m][nf] = __builtin_amdgcn_mfma_f32_16x16x32_bf16(af[m], bfr[nf], acc[m][nf], 0, 0, 0);
  }

  // epilogue: C/D layout col=lane&15, row=(lane>>4)*4+reg  [m89-verified]
  float sd = 0.f, sy = 0.f;
  #pragma unroll
  for (int m = 0; m < 4; ++m) {
    #pragma unroll
    for (int nf = 0; nf < 4; ++nf) {
      #pragma unroll
      for (int r = 0; r < 4; ++r) {
        int t = t0 + wr * 64 + m * 16 + lg * 4 + r;
        int n = n0 + wc * 64 + nf * 16 + lr;
        size_t idx = (size_t)t * N_DIM + n;
        float x = acc[m][nf][r];
        float y = Y[idx];
        float d = y - x;
        sd += d * d; sy += y * y;
        Xrec[idx] = x;
      }
    }
  }

  red[tid] = sd; red[256 + tid] = sy;
  __syncthreads();
  for (int s2 = 128; s2 > 0; s2 >>= 1) {
    if (tid < s2) { red[tid] += red[tid + s2]; red[256 + tid] += red[256 + tid + s2]; }
    __syncthreads();
  }
  if (tid == 0) {
    atomicAdd(acc_g,     (double)red[0]);
    atomicAdd(acc_g + 1, (double)red[256]);
  }
}

// ---------------- kernel E: finalize err ----------------
__global__ void k_err(const double* __restrict__ acc, float* __restrict__ out_tail) {
  out_tail[0] = (float)sqrt(acc[0] / acc[1]);
}

extern "C" void kernel_launch(void* const* d_in, const int* in_sizes, int n_in,
                              void* d_out, int out_size, void* d_ws, size_t ws_size,
                              hipStream_t stream) {
  const float* X_train = (const float*)d_in[1];
  const float* Y       = (const float*)d_in[2];
  const float* temp    = (const float*)d_in[3];
  const float* phi     = (const float*)d_in[4];
  const float* A_tilde = (const float*)d_in[5];
  const float* U       = (const float*)d_in[6];
  const float* logits  = (const float*)d_in[7];
  float* out = (float*)d_out;
  float* out_tail = out + (size_t)T_DIM * N_DIM;

  // workspace layout (bytes)
  char* w = (char*)d_ws;
  double* acc          = (double*)w;                     // @0, 16 B
  float* Wm            = (float*)(w + 64);               // 13*16384 B -> ends 213056
  float* xh0           = (float*)(w + 213056);           // 256 B
  float* part          = (float*)(w + 213312);           // 16384 B -> ends 229696
  unsigned short* uh   = (unsigned short*)(w + 262144);  // 512 KiB
  unsigned short* ul   = (unsigned short*)(w + 786432);  // 512 KiB
  unsigned short* xhi  = (unsigned short*)(w + 1310720); // 1 MiB
  unsigned short* xlo  = (unsigned short*)(w + 2359296); // 1 MiB -> ends 3407872

  k_xh0_part<<<64, 64, 0, stream>>>(U, X_train, part, acc);
  k_usplit<<<(N_DIM * L / 4) / 256, 256, 0, stream>>>(U, uh, ul);
  k_prep<<<1, 256, 0, stream>>>(A_tilde, phi, logits, temp, part, Wm, xh0, out_tail);
  k_states<<<N_CHUNK, 64, 0, stream>>>(Wm, xh0, xhi, xlo);
  k_xrec<<<2048, 256, 0, stream>>>(xhi, xlo, uh, ul, Y, out, acc);
  k_err<<<1, 1, 0, stream>>>(acc, out_tail);
}